// Round 1
// baseline (635.212 us; speedup 1.0000x reference)
//
#include <hip/hip_runtime.h>
#include <hip/hip_bf16.h>

#define T_LEN 2048
#define BB    128
#define CC    128
#define EE    32
#define HH    64
#define PRED  336

// ---------------------------------------------------------------------------
// Kernel A: per-batch encode.  Only channel 0 of x is used by the reference.
// t0 = 7-tap edge-clamped moving average of x[:, :, 0]; r0 = x0 - t0.
// v[b,e] = tanh(t0.We_trend) + tanh(r0.We_weekly) + tanh(r0.We_daily)
//        + tanh(r0.We_resid)   (biases are included for generality)
// ---------------------------------------------------------------------------
__global__ __launch_bounds__(256) void encode_kernel(
    const float* __restrict__ x,
    const float* __restrict__ WeT, const float* __restrict__ beT,
    const float* __restrict__ WeW, const float* __restrict__ beW,
    const float* __restrict__ WeD, const float* __restrict__ beD,
    const float* __restrict__ WeR, const float* __restrict__ beR,
    float* __restrict__ vout)
{
    __shared__ __align__(16) float s_x [T_LEN];
    __shared__ __align__(16) float s_t0[T_LEN];
    __shared__ __align__(16) float s_r0[T_LEN];
    __shared__ __align__(16) float s_part[4 * 32 * 32];   // [mat][chunk][e]

    const int tid = threadIdx.x;
    const int b   = blockIdx.x;
    const float* xb = x + (size_t)b * T_LEN * CC;

    // stage channel 0 (strided global reads, one line each — ~2048 per block)
    for (int t = tid; t < T_LEN; t += 256) s_x[t] = xb[(size_t)t * CC];
    __syncthreads();

    // 7-tap moving average with edge clamp
    for (int t = tid; t < T_LEN; t += 256) {
        float s = 0.f;
        #pragma unroll
        for (int j = -3; j <= 3; ++j) {
            int i = t + j;
            i = i < 0 ? 0 : (i > T_LEN - 1 ? T_LEN - 1 : i);
            s += s_x[i];
        }
        float tm = s * (1.0f / 7.0f);
        s_t0[t] = tm;
        s_r0[t] = s_x[t] - tm;
    }
    __syncthreads();

    // 4 GEMVs: thread handles e-group eg (4 e's via float4) over an
    // interleaved t-slice (t = tt*32 + chunk) -> conflict-free s_t0/s_r0 reads.
    const int eg    = tid & 7;          // e0 = eg*4
    const int chunk = (tid >> 3) & 31;  // 0..31
    float4 a0 = {0,0,0,0}, a1 = a0, a2 = a0, a3 = a0;
    const float4* WT4 = (const float4*)WeT;
    const float4* WW4 = (const float4*)WeW;
    const float4* WD4 = (const float4*)WeD;
    const float4* WR4 = (const float4*)WeR;
    #pragma unroll 4
    for (int tt = 0; tt < 64; ++tt) {
        int t = tt * 32 + chunk;
        float t0v = s_t0[t], r0v = s_r0[t];
        int wi = t * 8 + eg;
        float4 w;
        w = WT4[wi]; a0.x += t0v*w.x; a0.y += t0v*w.y; a0.z += t0v*w.z; a0.w += t0v*w.w;
        w = WW4[wi]; a1.x += r0v*w.x; a1.y += r0v*w.y; a1.z += r0v*w.z; a1.w += r0v*w.w;
        w = WD4[wi]; a2.x += r0v*w.x; a2.y += r0v*w.y; a2.z += r0v*w.z; a2.w += r0v*w.w;
        w = WR4[wi]; a3.x += r0v*w.x; a3.y += r0v*w.y; a3.z += r0v*w.z; a3.w += r0v*w.w;
    }
    float4* part4 = (float4*)s_part;
    part4[0*256 + chunk*8 + eg] = a0;
    part4[1*256 + chunk*8 + eg] = a1;
    part4[2*256 + chunk*8 + eg] = a2;
    part4[3*256 + chunk*8 + eg] = a3;
    __syncthreads();

    if (tid < EE) {
        const int e = tid;
        float s0 = 0.f, s1 = 0.f, s2 = 0.f, s3 = 0.f;
        #pragma unroll
        for (int ch = 0; ch < 32; ++ch) {
            s0 += s_part[0*1024 + ch*32 + e];
            s1 += s_part[1*1024 + ch*32 + e];
            s2 += s_part[2*1024 + ch*32 + e];
            s3 += s_part[3*1024 + ch*32 + e];
        }
        float v = tanhf(s0 + beT[e]) + tanhf(s1 + beW[e])
                + tanhf(s2 + beD[e]) + tanhf(s3 + beR[e]);
        vout[b * EE + e] = v;
    }
}

// ---------------------------------------------------------------------------
// Kernel B: the 336-step scan.  logmap0(expmap0(v)) == v identically, so the
// hyperbolic maps cancel and the recurrence is Euclidean in tv-space:
//   u  = silu(tv@Wd_in + bd_in) * sigmoid(tv@Wd_gate + bd_gate)
//   tv = tv + u@Wd_out + bd_out
//   pred[n] = tv@Wr + br
// One wave (64 lanes) per batch element; all weights in LDS; tv double-
// buffered -> 2 barriers/step (near-free for a 1-wave block).
// ---------------------------------------------------------------------------
__global__ __launch_bounds__(64) void scan_kernel(
    const float* __restrict__ Wdin, const float* __restrict__ bdin,
    const float* __restrict__ Wdg,  const float* __restrict__ bdg,
    const float* __restrict__ Wdo,  const float* __restrict__ bdo,
    const float* __restrict__ Wr,   const float* __restrict__ br,
    const float* __restrict__ vin,  float* __restrict__ out)
{
    __shared__ __align__(16) float s_wig[EE * HH * 2];  // [e][h]{in,gate} 16KB
    __shared__ __align__(16) float s_wdo[HH * EE];      // [h][e]           8KB
    __shared__ __align__(16) float s_wr [EE * CC];      // [e][c]          16KB
    __shared__ __align__(16) float s_big[HH * 2];       // {bd_in,bd_gate}[h]
    __shared__ __align__(16) float s_bdo[EE];
    __shared__ __align__(16) float s_br [CC];
    __shared__ __align__(16) float s_tv [2][EE];        // double-buffered state
    __shared__ __align__(16) float s_u  [HH];

    const int lane = threadIdx.x;
    const int b    = blockIdx.x;

    for (int i = lane; i < EE * HH; i += 64) {
        s_wig[i * 2    ] = Wdin[i];
        s_wig[i * 2 + 1] = Wdg[i];
        s_wdo[i]         = Wdo[i];
    }
    for (int i = lane; i < EE * CC; i += 64) s_wr[i] = Wr[i];
    s_big[lane * 2    ] = bdin[lane];
    s_big[lane * 2 + 1] = bdg[lane];
    if (lane < EE) s_bdo[lane] = bdo[lane];
    for (int i = lane; i < CC; i += 64) s_br[i] = br[i];
    if (lane < EE) s_tv[0][lane] = vin[b * EE + lane];
    __syncthreads();

    const int e  = lane & 31;
    const int hb = lane & 32;          // h-half this lane reduces in phase 2
    float* outb = out + (size_t)b * PRED * CC;

    for (int n = 0; n < PRED; ++n) {
        const int sel = n & 1;

        // -------- phase 1: lane h computes a,g; u[h] = silu(a)*sigmoid(g)
        float a = s_big[lane * 2], g = s_big[lane * 2 + 1];
        #pragma unroll
        for (int e4 = 0; e4 < 8; ++e4) {
            float4 t = ((const float4*)s_tv[sel])[e4];
            const float2* w = ((const float2*)s_wig) + (e4 * 4) * 64 + lane;
            float2 w0 = w[0], w1 = w[64], w2 = w[128], w3 = w[192];
            a += t.x * w0.x; g += t.x * w0.y;
            a += t.y * w1.x; g += t.y * w1.y;
            a += t.z * w2.x; g += t.z * w2.y;
            a += t.w * w3.x; g += t.w * w3.y;
        }
        float u = (a / (1.f + __expf(-a))) * (1.f / (1.f + __expf(-g)));
        s_u[lane] = u;
        __syncthreads();

        // -------- phase 2: dv[e] = sum_h u[h]*Wd_out[h][e], h split by half
        float dv = 0.f;
        #pragma unroll
        for (int h4 = 0; h4 < 8; ++h4) {
            float4 uu = ((const float4*)(s_u + hb))[h4];
            const float* wd = s_wdo + (hb + h4 * 4) * 32 + e;
            dv += uu.x * wd[0] + uu.y * wd[32] + uu.z * wd[64] + uu.w * wd[96];
        }
        dv += __shfl_xor(dv, 32);
        float tvn = s_tv[sel][e] + dv + s_bdo[e];
        if (lane < 32) s_tv[sel ^ 1][lane] = tvn;
        __syncthreads();

        // -------- phase 3: pred[c] = tv_new @ Wr + br, c = lane and lane+64
        float p0 = s_br[lane], p1 = s_br[lane + 64];
        #pragma unroll
        for (int e4 = 0; e4 < 8; ++e4) {
            float4 t = ((const float4*)s_tv[sel ^ 1])[e4];
            const float* wr = s_wr + (e4 * 4) * 128 + lane;
            p0 += t.x * wr[0]  + t.y * wr[128] + t.z * wr[256] + t.w * wr[384];
            p1 += t.x * wr[64] + t.y * wr[192] + t.z * wr[320] + t.w * wr[448];
        }
        float* op = outb + n * CC;
        op[lane]      = p0;
        op[lane + 64] = p1;
    }
}

extern "C" void kernel_launch(void* const* d_in, const int* in_sizes, int n_in,
                              void* d_out, int out_size, void* d_ws, size_t ws_size,
                              hipStream_t stream)
{
    const float* x    = (const float*)d_in[0];
    const float* WeT  = (const float*)d_in[1];
    const float* beT  = (const float*)d_in[2];
    const float* WeW  = (const float*)d_in[3];
    const float* beW  = (const float*)d_in[4];
    const float* WeD  = (const float*)d_in[5];
    const float* beD  = (const float*)d_in[6];
    const float* WeR  = (const float*)d_in[7];
    const float* beR  = (const float*)d_in[8];
    const float* Wdin = (const float*)d_in[9];
    const float* bdin = (const float*)d_in[10];
    const float* Wdg  = (const float*)d_in[11];
    const float* bdg  = (const float*)d_in[12];
    const float* Wdo  = (const float*)d_in[13];
    const float* bdo  = (const float*)d_in[14];
    const float* Wr   = (const float*)d_in[15];
    const float* br   = (const float*)d_in[16];

    float* out = (float*)d_out;
    float* vws = (float*)d_ws;   // 128*32 floats of scratch for v

    encode_kernel<<<BB, 256, 0, stream>>>(x, WeT, beT, WeW, beW, WeD, beD,
                                          WeR, beR, vws);
    scan_kernel<<<BB, 64, 0, stream>>>(Wdin, bdin, Wdg, bdg, Wdo, bdo,
                                       Wr, br, vws, out);
}

// Round 2
// 601.327 us; speedup vs baseline: 1.0564x; 1.0564x over previous
//
#include <hip/hip_runtime.h>
#include <hip/hip_bf16.h>

#define T_LEN 2048
#define BB    128
#define CC    128
#define EE    32
#define HH    64
#define PRED  336
#define NSL   8           // T-slices for encode
#define SLT   (T_LEN/NSL) // 256 t per slice

// ---------------------------------------------------------------------------
// Kernel A: encode partials. grid (B, NSL). Only channel 0 of x is used.
// Each block: 7-tap edge-clamped moving average over its t-slice (+halo),
// then partial GEMV sums for the 4 encoder matrices -> P[sl][b][m*32+e].
// ---------------------------------------------------------------------------
__global__ __launch_bounds__(256) void encode_kernel(
    const float* __restrict__ x,
    const float* __restrict__ WeT, const float* __restrict__ WeW,
    const float* __restrict__ WeD, const float* __restrict__ WeR,
    float* __restrict__ P)
{
    __shared__ __align__(16) float s_x [SLT + 6];
    __shared__ __align__(16) float s_tr[SLT];
    __shared__ __align__(16) float s_rs[SLT];
    __shared__ __align__(16) float s_part[4][8][32];

    const int tid  = threadIdx.x;
    const int b    = blockIdx.x;
    const int sl   = blockIdx.y;
    const int base = sl * SLT;
    const float* xb = x + (size_t)b * T_LEN * CC;

    // channel-0 slice with halo, edge-clamped
    for (int i = tid; i < SLT + 6; i += 256) {
        int t = base - 3 + i;
        t = t < 0 ? 0 : (t > T_LEN - 1 ? T_LEN - 1 : t);
        s_x[i] = xb[(size_t)t * CC];
    }
    __syncthreads();

    {   // moving average (s_x index lt+3 == global t)
        const int lt = tid;
        float s = 0.f;
        #pragma unroll
        for (int j = 0; j < 7; ++j) s += s_x[lt + j];
        float tm = s * (1.0f / 7.0f);
        s_tr[lt] = tm;
        s_rs[lt] = s_x[lt + 3] - tm;
    }
    __syncthreads();

    const int e  = tid & 31;
    const int tg = tid >> 5;
    float a0 = 0.f, a1 = 0.f, a2 = 0.f, a3 = 0.f;
    #pragma unroll 4
    for (int j = 0; j < 32; ++j) {
        int lt = tg * 32 + j;
        int wi = (base + lt) * EE + e;
        float tv = s_tr[lt], rv = s_rs[lt];
        a0 += tv * WeT[wi];
        a1 += rv * WeW[wi];
        a2 += rv * WeD[wi];
        a3 += rv * WeR[wi];
    }
    s_part[0][tg][e] = a0;
    s_part[1][tg][e] = a1;
    s_part[2][tg][e] = a2;
    s_part[3][tg][e] = a3;
    __syncthreads();

    if (tid < 128) {
        int m = tid >> 5, e2 = tid & 31;
        float s = 0.f;
        #pragma unroll
        for (int g = 0; g < 8; ++g) s += s_part[m][g][e2];
        P[((size_t)sl * BB + b) * 128 + tid] = s;
    }
}

// ---------------------------------------------------------------------------
// Kernel B: finalize encode + 336-step scan.  logmap0(expmap0(v)) == v, so
// the recurrence is Euclidean:
//   u  = silu(tv@Wd_in+b) * sigmoid(tv@Wd_gate+b)
//   tv = tv + u@Wd_out + bd_out ;  pred[n] = tv@Wr + br
// One wave per batch element.  ALL weights in registers (~160 VGPR/lane);
// per step only two LDS broadcast roundtrips (u and tv) + 2 barriers.
// ---------------------------------------------------------------------------
__global__ __launch_bounds__(64, 1) void scan_kernel(
    const float* __restrict__ P,
    const float* __restrict__ beT, const float* __restrict__ beW,
    const float* __restrict__ beD, const float* __restrict__ beR,
    const float* __restrict__ Wdin, const float* __restrict__ bdin,
    const float* __restrict__ Wdg,  const float* __restrict__ bdg,
    const float* __restrict__ Wdo,  const float* __restrict__ bdo,
    const float* __restrict__ Wr,   const float* __restrict__ br,
    float* __restrict__ out)
{
    __shared__ __align__(16) float s_tv[EE];
    __shared__ __align__(16) float s_u [HH];

    const int lane = threadIdx.x;
    const int b    = blockIdx.x;
    const int e    = lane & 31;
    const int hb   = lane & 32;
    const int c0   = 2 * lane;

    // ---- finalize encode: v[e] = sum of 4 tanh'd slice-sums
    if (lane < EE) {
        float s0 = 0.f, s1 = 0.f, s2 = 0.f, s3 = 0.f;
        #pragma unroll
        for (int sl = 0; sl < NSL; ++sl) {
            const float* p = P + ((size_t)sl * BB + b) * 128;
            s0 += p[0 * 32 + lane];
            s1 += p[1 * 32 + lane];
            s2 += p[2 * 32 + lane];
            s3 += p[3 * 32 + lane];
        }
        s_tv[lane] = tanhf(s0 + beT[lane]) + tanhf(s1 + beW[lane])
                   + tanhf(s2 + beD[lane]) + tanhf(s3 + beR[lane]);
    }

    // ---- hoist all weights into registers (loop-invariant)
    float w_a[EE], w_g[EE], w_o[EE], w_r0[EE], w_r1[EE];
    #pragma unroll
    for (int i = 0; i < EE; ++i) {
        w_a[i] = Wdin[i * HH + lane];          // Wd_in[e][h=lane]
        w_g[i] = Wdg [i * HH + lane];          // Wd_gate[e][h=lane]
        w_o[i] = Wdo [(hb + i) * EE + e];      // Wd_out[hb+i][e]
        float2 wr2 = ((const float2*)(Wr + i * CC))[lane];  // Wr[e][2*lane(+1)]
        w_r0[i] = wr2.x;
        w_r1[i] = wr2.y;
    }
    const float b_a = bdin[lane], b_g = bdg[lane], b_o = bdo[e];
    const float2 br2 = ((const float2*)br)[lane];
    __syncthreads();

    float t[EE];
    #pragma unroll
    for (int i = 0; i < EE / 4; ++i)
        ((float4*)t)[i] = ((const float4*)s_tv)[i];

    float2* outb = (float2*)(out + (size_t)b * PRED * CC);

    for (int n = 0; n < PRED; ++n) {
        // -------- phase 1: a,g for h=lane (4-way accumulator trees)
        float a0 = 0.f, a1 = 0.f, a2 = 0.f, a3 = 0.f;
        float g0 = 0.f, g1 = 0.f, g2 = 0.f, g3 = 0.f;
        #pragma unroll
        for (int i = 0; i < EE; i += 4) {
            a0 += t[i    ] * w_a[i    ]; g0 += t[i    ] * w_g[i    ];
            a1 += t[i + 1] * w_a[i + 1]; g1 += t[i + 1] * w_g[i + 1];
            a2 += t[i + 2] * w_a[i + 2]; g2 += t[i + 2] * w_g[i + 2];
            a3 += t[i + 3] * w_a[i + 3]; g3 += t[i + 3] * w_g[i + 3];
        }
        float a = (a0 + a1) + (a2 + a3) + b_a;
        float g = (g0 + g1) + (g2 + g3) + b_g;
        float u = (a / (1.f + __expf(-a))) * (1.f / (1.f + __expf(-g)));
        s_u[lane] = u;
        __syncthreads();

        // -------- phase 2: dv[e] over this lane's h-half, then fold halves
        float d0 = 0.f, d1 = 0.f, d2 = 0.f, d3 = 0.f;
        #pragma unroll
        for (int k4 = 0; k4 < EE / 4; ++k4) {
            float4 uu = ((const float4*)(s_u + hb))[k4];
            d0 += uu.x * w_o[k4 * 4    ];
            d1 += uu.y * w_o[k4 * 4 + 1];
            d2 += uu.z * w_o[k4 * 4 + 2];
            d3 += uu.w * w_o[k4 * 4 + 3];
        }
        float dv = (d0 + d1) + (d2 + d3);
        dv += __shfl_xor(dv, 32);
        float tvn = t[e] + dv + b_o;   // note: t[e] is OLD tv (regs), safe
        s_tv[e] = tvn;                 // both halves write identical value
        __syncthreads();

        #pragma unroll
        for (int i = 0; i < EE / 4; ++i)
            ((float4*)t)[i] = ((const float4*)s_tv)[i];

        // -------- phase 3: pred[c0], pred[c0+1]
        float p0 = 0.f, p1 = 0.f, q0 = 0.f, q1 = 0.f;
        #pragma unroll
        for (int i = 0; i < EE; i += 2) {
            p0 += t[i    ] * w_r0[i    ]; q0 += t[i    ] * w_r1[i    ];
            p1 += t[i + 1] * w_r0[i + 1]; q1 += t[i + 1] * w_r1[i + 1];
        }
        float2 pr;
        pr.x = p0 + p1 + br2.x;
        pr.y = q0 + q1 + br2.y;
        outb[n * (CC / 2) + lane] = pr;
    }
}

extern "C" void kernel_launch(void* const* d_in, const int* in_sizes, int n_in,
                              void* d_out, int out_size, void* d_ws, size_t ws_size,
                              hipStream_t stream)
{
    const float* x    = (const float*)d_in[0];
    const float* WeT  = (const float*)d_in[1];
    const float* beT  = (const float*)d_in[2];
    const float* WeW  = (const float*)d_in[3];
    const float* beW  = (const float*)d_in[4];
    const float* WeD  = (const float*)d_in[5];
    const float* beD  = (const float*)d_in[6];
    const float* WeR  = (const float*)d_in[7];
    const float* beR  = (const float*)d_in[8];
    const float* Wdin = (const float*)d_in[9];
    const float* bdin = (const float*)d_in[10];
    const float* Wdg  = (const float*)d_in[11];
    const float* bdg  = (const float*)d_in[12];
    const float* Wdo  = (const float*)d_in[13];
    const float* bdo  = (const float*)d_in[14];
    const float* Wr   = (const float*)d_in[15];
    const float* br   = (const float*)d_in[16];

    float* out = (float*)d_out;
    float* P   = (float*)d_ws;   // NSL*BB*128 floats = 512 KB partials

    encode_kernel<<<dim3(BB, NSL), 256, 0, stream>>>(x, WeT, WeW, WeD, WeR, P);
    scan_kernel<<<BB, 64, 0, stream>>>(P, beT, beW, beD, beR,
                                       Wdin, bdin, Wdg, bdg, Wdo, bdo,
                                       Wr, br, out);
}

// Round 3
// 411.146 us; speedup vs baseline: 1.5450x; 1.4626x over previous
//
#include <hip/hip_runtime.h>

#define T_LEN 2048
#define BB    128
#define CC    128
#define EE    32
#define HH    64
#define PRED  336

#define REP32(F) F(0) F(1) F(2) F(3) F(4) F(5) F(6) F(7) \
                 F(8) F(9) F(10) F(11) F(12) F(13) F(14) F(15) \
                 F(16) F(17) F(18) F(19) F(20) F(21) F(22) F(23) \
                 F(24) F(25) F(26) F(27) F(28) F(29) F(30) F(31)

// ---------------------------------------------------------------------------
// One kernel per batch element (grid = 128, block = 256).
// Prologue (all 4 waves): channel-0 extract, 7-tap edge-clamped moving
// average, 4 encoder GEMVs (2048x32 each) -> v = s_tv[32] in LDS.
// Scan (wave 0 only, no barriers): logmap0(expmap0(v)) == v identically, so
// the recurrence is Euclidean:
//   u  = silu(tv@Wd_in+b) * sigmoid(tv@Wd_gate+b)
//   tv = tv + u@Wd_out + bd_out ;  pred[n] = tv@Wr + br
// tv[32] is REPLICATED in every lane's registers (identical update in all
// lanes -> zero communication). Only u crosses lanes, via ds_swizzle
// broadcasts (no LDS memory, no barriers, immediate offsets).
// ---------------------------------------------------------------------------
__global__ __launch_bounds__(256, 1) void fused_kernel(
    const float* __restrict__ x,
    const float* __restrict__ WeT,  const float* __restrict__ beT,
    const float* __restrict__ WeW,  const float* __restrict__ beW,
    const float* __restrict__ WeD,  const float* __restrict__ beD,
    const float* __restrict__ WeR,  const float* __restrict__ beR,
    const float* __restrict__ Wdin, const float* __restrict__ bdin,
    const float* __restrict__ Wdg,  const float* __restrict__ bdg,
    const float* __restrict__ Wdo,  const float* __restrict__ bdo,
    const float* __restrict__ Wr,   const float* __restrict__ br,
    float* __restrict__ out)
{
    __shared__ __align__(16) float s_x [T_LEN + 6];
    __shared__ __align__(16) float s_tr[T_LEN];
    __shared__ __align__(16) float s_rs[T_LEN];
    __shared__ __align__(16) float s_part[4][8][32];
    __shared__ __align__(16) float s_tv[EE];

    const int tid = threadIdx.x;
    const int b   = blockIdx.x;
    const float* xb = x + (size_t)b * T_LEN * CC;

    // ---- channel-0 slice with halo, edge-clamped
    for (int i = tid; i < T_LEN + 6; i += 256) {
        int t = i - 3;
        t = t < 0 ? 0 : (t > T_LEN - 1 ? T_LEN - 1 : t);
        s_x[i] = xb[(size_t)t * CC];
    }
    __syncthreads();

    // ---- 7-tap moving average (s_x index t+3 == global t)
    for (int t = tid; t < T_LEN; t += 256) {
        float s = 0.f;
        #pragma unroll
        for (int j = 0; j < 7; ++j) s += s_x[t + j];
        float tm = s * (1.0f / 7.0f);
        s_tr[t] = tm;
        s_rs[t] = s_x[t + 3] - tm;
    }
    __syncthreads();

    // ---- 4 encoder GEMV partials: e = tid&31, 8 t-groups of 256
    {
        const int e = tid & 31, tg = tid >> 5;
        float a0 = 0.f, a1 = 0.f, a2 = 0.f, a3 = 0.f;
        #pragma unroll 4
        for (int j = 0; j < 256; ++j) {
            int lt = tg * 256 + j;
            int wi = lt * EE + e;
            float trv = s_tr[lt], rsv = s_rs[lt];
            a0 += trv * WeT[wi];
            a1 += rsv * WeW[wi];
            a2 += rsv * WeD[wi];
            a3 += rsv * WeR[wi];
        }
        s_part[0][tg][e] = a0;
        s_part[1][tg][e] = a1;
        s_part[2][tg][e] = a2;
        s_part[3][tg][e] = a3;
    }
    __syncthreads();

    if (tid < EE) {
        float s0 = 0.f, s1 = 0.f, s2 = 0.f, s3 = 0.f;
        #pragma unroll
        for (int g = 0; g < 8; ++g) {
            s0 += s_part[0][g][tid];
            s1 += s_part[1][g][tid];
            s2 += s_part[2][g][tid];
            s3 += s_part[3][g][tid];
        }
        s_tv[tid] = tanhf(s0 + beT[tid]) + tanhf(s1 + beW[tid])
                  + tanhf(s2 + beD[tid]) + tanhf(s3 + beR[tid]);
    }
    __syncthreads();

    if (tid >= 64) return;            // waves 1-3 done; wave 0 runs the scan
    const int lane = tid;
    const int e    = lane & 31;
    const int hb   = lane & 32;

    // ---- loop-invariant weights into registers
    float w_a[EE], w_g[EE], w_o[EE], w_r0[EE], w_r1[EE];
    #pragma unroll
    for (int i = 0; i < EE; ++i) {
        w_a[i] = Wdin[i * HH + lane];            // Wd_in [e=i][h=lane]
        w_g[i] = Wdg [i * HH + lane];            // Wd_gate[e=i][h=lane]
        w_o[i] = Wdo [(hb + i) * EE + e];        // Wd_out[h=hb+i][e]
        float2 w2 = *(const float2*)(Wr + i * CC + 2 * lane);
        w_r0[i] = w2.x;                          // Wr[e=i][c=2*lane]
        w_r1[i] = w2.y;                          // Wr[e=i][c=2*lane+1]
    }
    const float  b_a = bdin[lane], b_g = bdg[lane], b_o = bdo[e];
    const float2 br2 = *(const float2*)(br + 2 * lane);

    float tv[EE];                                // replicated state
    #pragma unroll
    for (int i = 0; i < EE; ++i) tv[i] = s_tv[i];
    float tv_mine = s_tv[e];                     // this lane's tv[e]

    float2* outb = (float2*)(out + (size_t)b * PRED * CC);

    for (int n = 0; n < PRED; ++n) {
        // -------- phase 1: a,g for h=lane (pure register FMAs)
        float a0 = b_a, a1 = 0.f, a2 = 0.f, a3 = 0.f;
        float g0 = b_g, g1 = 0.f, g2 = 0.f, g3 = 0.f;
        #pragma unroll
        for (int i = 0; i < EE; i += 4) {
            a0 += tv[i    ] * w_a[i    ]; g0 += tv[i    ] * w_g[i    ];
            a1 += tv[i + 1] * w_a[i + 1]; g1 += tv[i + 1] * w_g[i + 1];
            a2 += tv[i + 2] * w_a[i + 2]; g2 += tv[i + 2] * w_g[i + 2];
            a3 += tv[i + 3] * w_a[i + 3]; g3 += tv[i + 3] * w_g[i + 3];
        }
        float a = (a0 + a1) + (a2 + a3);
        float g = (g0 + g1) + (g2 + g3);
        float u = a / (1.f + __expf(-a)) * (1.f / (1.f + __expf(-g)));

        // -------- phase 2: dv[e] over this lane's h-half via ds_swizzle
        // broadcasts (lane hb+j of own half), then fold the two halves.
        int   ui = __float_as_int(u);
        float dva[4] = {0.f, 0.f, 0.f, 0.f};
        #define GATH(j) { \
            float uj = __int_as_float(__builtin_amdgcn_ds_swizzle(ui, (j) << 5)); \
            dva[(j) & 3] += uj * w_o[(j)]; }
        REP32(GATH)
        #undef GATH
        float dv = (dva[0] + dva[1]) + (dva[2] + dva[3]);
        dv += __shfl_xor(dv, 32);                // fold h-halves
        float tvn = tv_mine + dv + b_o;          // valid in both halves
        tv_mine = tvn;

        // -------- re-replicate tv[32] from lanes 0..31 of each half
        int ti = __float_as_int(tvn);
        #define REPL(i) tv[(i)] = \
            __int_as_float(__builtin_amdgcn_ds_swizzle(ti, (i) << 5));
        REP32(REPL)
        #undef REPL

        // -------- phase 3: pred[c=2*lane], pred[c=2*lane+1]
        float p0 = br2.x, p1 = 0.f, q0 = br2.y, q1 = 0.f;
        #pragma unroll
        for (int i = 0; i < EE; i += 2) {
            p0 += tv[i    ] * w_r0[i    ]; q0 += tv[i    ] * w_r1[i    ];
            p1 += tv[i + 1] * w_r0[i + 1]; q1 += tv[i + 1] * w_r1[i + 1];
        }
        float2 pr; pr.x = p0 + p1; pr.y = q0 + q1;
        outb[lane] = pr;
        outb += CC / 2;
    }
}

extern "C" void kernel_launch(void* const* d_in, const int* in_sizes, int n_in,
                              void* d_out, int out_size, void* d_ws, size_t ws_size,
                              hipStream_t stream)
{
    const float* x    = (const float*)d_in[0];
    const float* WeT  = (const float*)d_in[1];
    const float* beT  = (const float*)d_in[2];
    const float* WeW  = (const float*)d_in[3];
    const float* beW  = (const float*)d_in[4];
    const float* WeD  = (const float*)d_in[5];
    const float* beD  = (const float*)d_in[6];
    const float* WeR  = (const float*)d_in[7];
    const float* beR  = (const float*)d_in[8];
    const float* Wdin = (const float*)d_in[9];
    const float* bdin = (const float*)d_in[10];
    const float* Wdg  = (const float*)d_in[11];
    const float* bdg  = (const float*)d_in[12];
    const float* Wdo  = (const float*)d_in[13];
    const float* bdo  = (const float*)d_in[14];
    const float* Wr   = (const float*)d_in[15];
    const float* br   = (const float*)d_in[16];

    fused_kernel<<<BB, 256, 0, stream>>>(x, WeT, beT, WeW, beW, WeD, beD,
                                         WeR, beR, Wdin, bdin, Wdg, bdg,
                                         Wdo, bdo, Wr, br, (float*)d_out);
}

// Round 4
// 384.761 us; speedup vs baseline: 1.6509x; 1.0686x over previous
//
#include <hip/hip_runtime.h>

typedef float v2f __attribute__((ext_vector_type(2)));

#define T_LEN 2048
#define BB    128
#define CC    128
#define EE    32
#define HH    64
#define PRED  336
#define CH    56          // steps per chunk
#define NCH   6           // 6*56 = 336

// workspace layout (floats)
#define WS_MAG 0          // [h'][h][2] = {M_in, M_g}       8192
#define WS_MR  8192       // [h'][c]    = W_o@Wr            8192
#define WS_CAG 16384      // [h][2]     = {b_o@W_in, b_o@W_g} 128
#define WS_CR  16512      // [c]        = b_o@Wr             128
#define WS_V   16640      // [b][e]     = encoder output    4096

__device__ __forceinline__ v2f mk2(float a, float b) { v2f t; t.x = a; t.y = b; return t; }

// ---------------------------------------------------------------------------
// Prep kernel.  Blocks 0..127: per-batch encode (channel 0 only): 7-tap
// edge-clamped moving average -> trend/resid, 4 tanh GEMVs -> v[b][32].
// Blocks 128..143: precompute M_ag = W_o@[W_in|W_g], M_r = W_o@Wr, c-vectors.
// ---------------------------------------------------------------------------
__global__ __launch_bounds__(256) void prep_kernel(
    const float* __restrict__ x,
    const float* __restrict__ WeT, const float* __restrict__ beT,
    const float* __restrict__ WeW, const float* __restrict__ beW,
    const float* __restrict__ WeD, const float* __restrict__ beD,
    const float* __restrict__ WeR, const float* __restrict__ beR,
    const float* __restrict__ Wdin, const float* __restrict__ Wdg,
    const float* __restrict__ Wdo,  const float* __restrict__ bdo,
    const float* __restrict__ Wr,
    float* __restrict__ ws)
{
    const int tid = threadIdx.x;

    if (blockIdx.x < BB) {
        __shared__ __align__(16) float s_x [T_LEN + 6];
        __shared__ __align__(16) float s_tr[T_LEN];
        __shared__ __align__(16) float s_rs[T_LEN];
        __shared__ __align__(16) float s_part[4][8][32];

        const int b = blockIdx.x;
        const float* xb = x + (size_t)b * T_LEN * CC;

        for (int i = tid; i < T_LEN + 6; i += 256) {
            int t = i - 3;
            t = t < 0 ? 0 : (t > T_LEN - 1 ? T_LEN - 1 : t);
            s_x[i] = xb[(size_t)t * CC];
        }
        __syncthreads();

        for (int t = tid; t < T_LEN; t += 256) {
            float s = 0.f;
            #pragma unroll
            for (int j = 0; j < 7; ++j) s += s_x[t + j];
            float tm = s * (1.0f / 7.0f);
            s_tr[t] = tm;
            s_rs[t] = s_x[t + 3] - tm;
        }
        __syncthreads();

        {
            const int e = tid & 31, tg = tid >> 5;
            float a0 = 0.f, a1 = 0.f, a2 = 0.f, a3 = 0.f;
            #pragma unroll 4
            for (int j = 0; j < 256; ++j) {
                int lt = tg * 256 + j;
                int wi = lt * EE + e;
                float trv = s_tr[lt], rsv = s_rs[lt];
                a0 += trv * WeT[wi];
                a1 += rsv * WeW[wi];
                a2 += rsv * WeD[wi];
                a3 += rsv * WeR[wi];
            }
            s_part[0][tg][e] = a0;
            s_part[1][tg][e] = a1;
            s_part[2][tg][e] = a2;
            s_part[3][tg][e] = a3;
        }
        __syncthreads();

        if (tid < EE) {
            float s0 = 0.f, s1 = 0.f, s2 = 0.f, s3 = 0.f;
            #pragma unroll
            for (int g = 0; g < 8; ++g) {
                s0 += s_part[0][g][tid];
                s1 += s_part[1][g][tid];
                s2 += s_part[2][g][tid];
                s3 += s_part[3][g][tid];
            }
            ws[WS_V + b * EE + tid] =
                  tanhf(s0 + beT[tid]) + tanhf(s1 + beW[tid])
                + tanhf(s2 + beD[tid]) + tanhf(s3 + beR[tid]);
        }
        return;
    }

    // ---- M precompute: 16 blocks x 256 threads = 4096 threads
    const int t0 = (blockIdx.x - BB) * 256 + tid;       // 0..4095
    const int hp = t0 >> 6;                             // h' = 0..63
    const int j  = t0 & 63;                             // h, or channel-pair
    float mi = 0.f, mg = 0.f, r0 = 0.f, r1 = 0.f;
    #pragma unroll 4
    for (int e = 0; e < EE; ++e) {
        float wo = Wdo[hp * EE + e];
        mi += wo * Wdin[e * HH + j];
        mg += wo * Wdg [e * HH + j];
        r0 += wo * Wr  [e * CC + 2 * j];
        r1 += wo * Wr  [e * CC + 2 * j + 1];
    }
    ws[WS_MAG + (hp * HH + j) * 2    ] = mi;
    ws[WS_MAG + (hp * HH + j) * 2 + 1] = mg;
    ws[WS_MR  + hp * CC + 2 * j      ] = r0;
    ws[WS_MR  + hp * CC + 2 * j + 1  ] = r1;

    if (t0 < HH) {
        float ci = 0.f, cg = 0.f;
        for (int e = 0; e < EE; ++e) {
            float bo = bdo[e];
            ci += bo * Wdin[e * HH + t0];
            cg += bo * Wdg [e * HH + t0];
        }
        ws[WS_CAG + t0 * 2    ] = ci;
        ws[WS_CAG + t0 * 2 + 1] = cg;
    } else if (t0 < HH + CC) {
        int c = t0 - HH;
        float cr = 0.f;
        for (int e = 0; e < EE; ++e) cr += bdo[e] * Wr[e * CC + c];
        ws[WS_CR + c] = cr;
    }
}

// ---------------------------------------------------------------------------
// Scan kernel: one block per batch element, 4 waves.
// Wave 0 (producer): state (A,G) per lane h; per step: u_h = silu(A)*sigm(G),
//   write u to ring, broadcast-read all 64 u, A,G += u@M_ag + c_ag.
//   ONE LDS roundtrip per step, no barriers inside a chunk.
// Waves 1-3 (consumers): track S = prefix-sum of u; for own steps (n%3==w-1)
//   emit pred_n = Q0 + S@M_r + (n+1)*c_r.  Chunk-level double buffer,
//   __syncthreads only at chunk boundaries (2 per 56 steps).
// ---------------------------------------------------------------------------
__global__ __launch_bounds__(256, 1) void scan_kernel(
    const float* __restrict__ ws,
    const float* __restrict__ Wdin, const float* __restrict__ bdin,
    const float* __restrict__ Wdg,  const float* __restrict__ bdg,
    const float* __restrict__ Wr,   const float* __restrict__ br,
    float* __restrict__ out)
{
    __shared__ __align__(16) float s_v[EE];
    __shared__ __align__(16) float s_u[2][CH][HH];     // 28672 B ring

    const int tid  = threadIdx.x;
    const int wid  = tid >> 6;
    const int lane = tid & 63;
    const int b    = blockIdx.x;

    if (tid < EE) s_v[tid] = ws[WS_V + b * EE + tid];
    __syncthreads();

    if (wid == 0) {
        // ================= producer =================
        v2f m_ag[HH];
        #pragma unroll
        for (int k = 0; k < HH; ++k)
            m_ag[k] = ((const v2f*)(ws + WS_MAG))[k * HH + lane];
        const v2f c_ag = ((const v2f*)(ws + WS_CAG))[lane];

        v2f ag = mk2(bdin[lane], bdg[lane]);
        for (int e = 0; e < EE; ++e) {
            float ve = s_v[e];
            ag.x += ve * Wdin[e * HH + lane];
            ag.y += ve * Wdg [e * HH + lane];
        }

        for (int c = 0; c < NCH + 1; ++c) {
            if (c < NCH) {
                float* ring = &s_u[c & 1][0][0];
                for (int i = 0; i < CH; ++i) {
                    float a = ag.x, g = ag.y;
                    float ea = __expf(-a), eg = __expf(-g);
                    float u = a * __builtin_amdgcn_rcpf((1.f + ea) * (1.f + eg));
                    ring[i * HH + lane] = u;

                    v2f acc = c_ag;
                    const float4* u4 = (const float4*)(ring + i * HH);
                    #pragma unroll
                    for (int k = 0; k < HH / 4; ++k) {
                        float4 q = u4[k];
                        acc += q.x * m_ag[4 * k    ];
                        acc += q.y * m_ag[4 * k + 1];
                        acc += q.z * m_ag[4 * k + 2];
                        acc += q.w * m_ag[4 * k + 3];
                    }
                    ag += acc;
                }
            }
            __syncthreads();
        }
    } else {
        // ================= consumers =================
        const int own = wid - 1;                       // handles n % 3 == own
        v2f m_r[HH];
        #pragma unroll
        for (int k = 0; k < HH; ++k)
            m_r[k] = ((const v2f*)(ws + WS_MR))[k * (CC / 2) + lane];
        const v2f c_r2 = ((const v2f*)(ws + WS_CR))[lane];

        v2f Q0 = ((const v2f*)br)[lane];
        for (int e = 0; e < EE; ++e) {
            float ve = s_v[e];
            Q0 += ve * ((const v2f*)(Wr + e * CC))[lane];
        }

        v2f S[HH / 2];
        #pragma unroll
        for (int k = 0; k < HH / 2; ++k) S[k] = mk2(0.f, 0.f);

        v2f* outb = (v2f*)(out + (size_t)b * PRED * CC);

        for (int c = 0; c < NCH + 1; ++c) {
            if (c > 0) {
                const float* ring = &s_u[(c - 1) & 1][0][0];
                const int n0 = (c - 1) * CH;
                int ph = n0 % 3;
                for (int i = 0; i < CH; ++i) {
                    const float4* u4 = (const float4*)(ring + i * HH);
                    #pragma unroll
                    for (int k = 0; k < HH / 4; ++k) {
                        float4 q = u4[k];
                        S[2 * k    ] += mk2(q.x, q.y);
                        S[2 * k + 1] += mk2(q.z, q.w);
                    }
                    if (ph == own) {                   // wave-uniform branch
                        int n = n0 + i;
                        v2f P = Q0 + (float)(n + 1) * c_r2;
                        #pragma unroll
                        for (int k = 0; k < HH / 2; ++k) {
                            P += S[k].x * m_r[2 * k    ];
                            P += S[k].y * m_r[2 * k + 1];
                        }
                        outb[(size_t)n * (CC / 2) + lane] = P;
                    }
                    ph = (ph == 2) ? 0 : ph + 1;
                }
            }
            __syncthreads();
        }
    }
}

extern "C" void kernel_launch(void* const* d_in, const int* in_sizes, int n_in,
                              void* d_out, int out_size, void* d_ws, size_t ws_size,
                              hipStream_t stream)
{
    const float* x    = (const float*)d_in[0];
    const float* WeT  = (const float*)d_in[1];
    const float* beT  = (const float*)d_in[2];
    const float* WeW  = (const float*)d_in[3];
    const float* beW  = (const float*)d_in[4];
    const float* WeD  = (const float*)d_in[5];
    const float* beD  = (const float*)d_in[6];
    const float* WeR  = (const float*)d_in[7];
    const float* beR  = (const float*)d_in[8];
    const float* Wdin = (const float*)d_in[9];
    const float* bdin = (const float*)d_in[10];
    const float* Wdg  = (const float*)d_in[11];
    const float* bdg  = (const float*)d_in[12];
    const float* Wdo  = (const float*)d_in[13];
    const float* bdo  = (const float*)d_in[14];
    const float* Wr   = (const float*)d_in[15];
    const float* br   = (const float*)d_in[16];

    float* ws  = (float*)d_ws;
    float* out = (float*)d_out;

    prep_kernel<<<BB + 16, 256, 0, stream>>>(x, WeT, beT, WeW, beW, WeD, beD,
                                             WeR, beR, Wdin, Wdg, Wdo, bdo,
                                             Wr, ws);
    scan_kernel<<<BB, 256, 0, stream>>>(ws, Wdin, bdin, Wdg, bdg, Wr, br, out);
}